// Round 6
// baseline (427.900 us; speedup 1.0000x reference)
//
#include <hip/hip_runtime.h>
#include <hip/hip_bf16.h>
#include <math.h>

#define NTOK 4096
#define CH 512
#define CQD 64
#define NBATCH 4
#define JB 128
#define IB 32

typedef __bf16 bf16x8 __attribute__((ext_vector_type(8)));
typedef float f32x4 __attribute__((ext_vector_type(4)));
typedef unsigned int u32x4 __attribute__((ext_vector_type(4)));
typedef unsigned short u16x4 __attribute__((ext_vector_type(4)));

__device__ __forceinline__ unsigned short f2bf(float f) {
  unsigned int u = __builtin_bit_cast(unsigned int, f);
  unsigned int r = (u + 0x7FFFu + ((u >> 16) & 1u)) >> 16;
  return (unsigned short)r;
}

__device__ __forceinline__ bf16x8 load_frag(const unsigned short* p) {
  u32x4 v = *reinterpret_cast<const u32x4*>(p);
  return __builtin_bit_cast(bf16x8, v);
}

// ---- K0a: transpose + convert x -> xT bf16 (B, N, 1024): [0..511]=xs, [512..1023]=xt
__global__ void k_transpose(const float* __restrict__ xs, const float* __restrict__ xt,
                            unsigned short* __restrict__ xT) {
  __shared__ unsigned short lds[64][66];
  int b = blockIdx.z;
  int n0 = blockIdx.x * 64;
  int c0 = blockIdx.y * 64;  // 0..1023
  const float* src = (c0 < CH) ? xs : xt;
  int cs0 = (c0 < CH) ? c0 : c0 - CH;
  int tid = threadIdx.x;
  int nn = tid & 63, cg = tid >> 6;
  const float* base = src + ((size_t)b * CH + cs0) * NTOK + n0;
  for (int cc = cg; cc < 64; cc += 4)
    lds[cc][nn] = f2bf(base[(size_t)cc * NTOK + nn]);
  __syncthreads();
  int cw = tid & 63, ng = tid >> 6;
  unsigned short* dst = xT + ((size_t)b * NTOK + n0) * 1024 + c0 + cw;
  for (int n2 = ng; n2 < 64; n2 += 4)
    dst[(size_t)n2 * 1024] = lds[cw][n2];
}

// ---- K0b: weights f32 -> bf16 (Wq, Wk, Wv = [Wvs | Wvt])
__global__ void k_weights(const float* __restrict__ Wq, const float* __restrict__ Wk,
                          const float* __restrict__ Wvs, const float* __restrict__ Wvt,
                          unsigned short* __restrict__ wq, unsigned short* __restrict__ wk,
                          unsigned short* __restrict__ wv) {
  int t = blockIdx.x * 256 + threadIdx.x;
  if (t < 32768) {
    wq[t] = f2bf(Wq[t]);
  } else if (t < 65536) {
    int j = t - 32768;
    wk[j] = f2bf(Wk[j]);
  } else {
    int j = t - 65536;
    if (j < 512 * 1024) {
      int c = j >> 10, k = j & 1023;
      float v = (k < 512) ? Wvs[c * 512 + k] : Wvt[c * 512 + (k - 512)];
      wv[j] = f2bf(v);
    }
  }
}

// ---- K1: projection GEMM. D[n][m] = sum_k xT[b][n][koff+k] * W[m][k] (+bias)
// mode 0: out[b][n][m] (N x 64) scalar bf16 stores (for Q, Kt)
// mode 1: out[b][m][n] (C x N) packed 4-wide bf16 stores (for V)
__global__ void __launch_bounds__(256)
k_proj(const unsigned short* __restrict__ xT, const unsigned short* __restrict__ W,
       const float* __restrict__ bias1, const float* __restrict__ bias2,
       unsigned short* __restrict__ out, int Kdim, int koff, int mode) {
  int b = blockIdx.z;
  int n0 = blockIdx.x * 256;
  int m0 = blockIdx.y * 64;
  int tid = threadIdx.x;
  int w = tid >> 6, l = tid & 63;
  int fr = l & 15, fk = l >> 4;
  f32x4 acc[4][4] = {};  // [nstrip][mfrag]
  const unsigned short* xbase =
      xT + ((size_t)b * NTOK + n0 + w * 64 + fr) * 1024 + koff + fk * 8;
  const unsigned short* wbase = W + ((size_t)(m0 + fr)) * Kdim + fk * 8;
  for (int k = 0; k < Kdim; k += 32) {
    bf16x8 a[4], bb[4];
#pragma unroll
    for (int ns = 0; ns < 4; ns++) a[ns] = load_frag(xbase + (size_t)ns * 16 * 1024 + k);
#pragma unroll
    for (int mf = 0; mf < 4; mf++) bb[mf] = load_frag(wbase + (size_t)mf * 16 * Kdim + k);
#pragma unroll
    for (int ns = 0; ns < 4; ns++)
#pragma unroll
      for (int mf = 0; mf < 4; mf++)
        acc[ns][mf] = __builtin_amdgcn_mfma_f32_16x16x32_bf16(a[ns], bb[mf], acc[ns][mf], 0, 0, 0);
  }
  if (mode == 0) {
#pragma unroll
    for (int ns = 0; ns < 4; ns++)
#pragma unroll
      for (int mf = 0; mf < 4; mf++) {
        int m = m0 + mf * 16 + fr;
        float bv = bias1[m];
        int nb = n0 + w * 64 + ns * 16 + fk * 4;
#pragma unroll
        for (int r = 0; r < 4; r++)
          out[((size_t)b * NTOK + nb + r) * CQD + m] = f2bf(acc[ns][mf][r] + bv);
      }
  } else {
#pragma unroll
    for (int ns = 0; ns < 4; ns++)
#pragma unroll
      for (int mf = 0; mf < 4; mf++) {
        int c = m0 + mf * 16 + fr;
        float bv = bias1[c] + bias2[c];
        int nb = n0 + w * 64 + ns * 16 + fk * 4;
        u16x4 pk;
#pragma unroll
        for (int r = 0; r < 4; r++) pk[r] = f2bf(acc[ns][mf][r] + bv);
        *reinterpret_cast<u16x4*>(out + ((size_t)b * CH + c) * NTOK + nb) = pk;
      }
  }
}

// ---- K2: fused attention+PV. Small blocks for TLP: 32 i-rows x 256 ch (cg half),
// 4 waves (wave = 64 ch + 32-j slice of P), grid 1024 -> 4 independent blocks/CU.
// Double-buffered P LDS, ONE barrier per 128-j tile; loadK one tile ahead;
// V loads at use (cross-block TLP hides latency). Verified 16x16x32 mappings.
__global__ void __launch_bounds__(256, 4)
k_pv(const unsigned short* __restrict__ Q, const unsigned short* __restrict__ Kt,
     const unsigned short* __restrict__ V, const float* __restrict__ xs,
     const float* __restrict__ xt, float* __restrict__ out) {
  __shared__ __align__(16) unsigned short P0_lds[IB * JB];  // 8KB, 256B rows, XOR-swizzled
  __shared__ __align__(16) unsigned short P1_lds[IB * JB];
  __shared__ float denom_lds[4][IB];
  __shared__ float rden_lds[IB];
  int b = blockIdx.z;
  int i0 = blockIdx.x * IB;
  int cg = blockIdx.y;  // 0..1
  int tid = threadIdx.x;
  int w = tid >> 6;   // wave 0..3
  int l = tid & 63;
  int fr = l & 15, fk = l >> 4;
  int c0 = cg * 256 + w * 64;

  // Q frags (B operand of S^T): col=lane&15 -> i = i0+f*16+fr, k = fk*8+e (+32 chained)
  bf16x8 qf[2][2];
#pragma unroll
  for (int f = 0; f < 2; f++) {
    const unsigned short* qb = Q + ((size_t)b * NTOK + i0 + f * 16 + fr) * CQD + fk * 8;
    qf[f][0] = load_frag(qb);
    qf[f][1] = load_frag(qb + 32);
  }
  float dsum[2] = {0.f, 0.f};  // per-lane partial, i = f*16 + fr
  f32x4 acc[2][4] = {};        // [is][cf]

  // K rows (A operand of S^T): row=lane&15 -> j = jn + w*32 + jf*16 + fr
  const unsigned short* kbase = Kt + ((size_t)b * NTOK + w * 32 + fr) * CQD + fk * 8;
  // V rows (B operand of PV): col=lane&15 -> c = c0+cf*16+fr
  const unsigned short* vbase = V + ((size_t)b * CH + c0 + fr) * NTOK + fk * 8;

  bf16x8 kf[2][2];  // K frags for the next phaseA tile [jf][half]
  auto loadK = [&](int jn) {
#pragma unroll
    for (int jf = 0; jf < 2; jf++) {
      kf[jf][0] = load_frag(kbase + (size_t)(jn + jf * 16) * CQD);
      kf[jf][1] = load_frag(kbase + (size_t)(jn + jf * 16) * CQD + 32);
    }
  };
  // phase A: P rows i0..i0+31 for j-tile at jn (uses kf), wave's cols w*32..w*32+31
  auto phaseA = [&](unsigned short* plds) {
    char* pb = reinterpret_cast<char*>(plds);
#pragma unroll
    for (int jf = 0; jf < 2; jf++)
#pragma unroll
      for (int f = 0; f < 2; f++) {
        f32x4 s = {};
        s = __builtin_amdgcn_mfma_f32_16x16x32_bf16(kf[jf][0], qf[f][0], s, 0, 0, 0);
        s = __builtin_amdgcn_mfma_f32_16x16x32_bf16(kf[jf][1], qf[f][1], s, 0, 0, 0);
        u16x4 pk;
#pragma unroll
        for (int r = 0; r < 4; r++) {
          float p = __expf(0.125f * s[r] - 8.0f);
          dsum[f] += p;
          pk[r] = f2bf(p);
        }
        int prow = f * 16 + fr;
        int col = w * 64 + jf * 32 + fk * 8;  // byte col = 2*(j - jn)
        *reinterpret_cast<u16x4*>(pb + prow * (JB * 2) + (col ^ ((prow & 7) << 4))) = pk;
      }
  };
  // phase B: acc += P(32x128) @ V^T, P from plds, V loaded at use
  auto phaseB = [&](int jc, const unsigned short* plds) {
    const char* pb = reinterpret_cast<const char*>(plds);
    __builtin_amdgcn_s_setprio(1);
#pragma unroll
    for (int js = 0; js < 4; js++) {
      bf16x8 pa[2];
#pragma unroll
      for (int is = 0; is < 2; is++) {
        int prow = is * 16 + fr;
        int byteoff = prow * (JB * 2) + ((js * 64 + fk * 16) ^ ((prow & 7) << 4));
        pa[is] = __builtin_bit_cast(bf16x8, *reinterpret_cast<const u32x4*>(pb + byteoff));
      }
#pragma unroll
      for (int cf = 0; cf < 4; cf++) {
        bf16x8 vf = load_frag(vbase + (size_t)cf * 16 * NTOK + jc + js * 32);
#pragma unroll
        for (int is = 0; is < 2; is++)
          acc[is][cf] = __builtin_amdgcn_mfma_f32_16x16x32_bf16(pa[is], vf, acc[is][cf], 0, 0, 0);
      }
    }
    __builtin_amdgcn_s_setprio(0);
  };

  constexpr int NT = NTOK / JB;  // 32
  // ---- prologue
  loadK(0);
  phaseA(P0_lds);
  loadK(JB);
  __syncthreads();

  for (int t = 0; t < NT; t += 2) {
    // half 1: P0 = P(t) ready, kf = K(t+1)
    phaseA(P1_lds);
    if (t + 2 < NT) loadK((t + 2) * JB);
    phaseB(t * JB, P0_lds);
    __syncthreads();
    // half 2: P1 = P(t+1) ready, kf = K(t+2)
    if (t + 2 < NT) {
      phaseA(P0_lds);
      if (t + 3 < NT) loadK((t + 3) * JB);
    }
    phaseB((t + 1) * JB, P1_lds);
    __syncthreads();
  }

  // ---- denominator: combine fk groups (lanes l, l^16, l^32, l^48 share i), then waves
#pragma unroll
  for (int f = 0; f < 2; f++) {
    float v = dsum[f];
    v += __shfl_xor(v, 16);
    v += __shfl_xor(v, 32);
    if (l < 16) denom_lds[w][f * 16 + l] = v;
  }
  __syncthreads();
  if (tid < IB) {
    float d = denom_lds[0][tid] + denom_lds[1][tid] + denom_lds[2][tid] + denom_lds[3][tid];
    rden_lds[tid] = 1.0f / d;
  }
  __syncthreads();

  // ---- epilogue: out = acc * rden + xs + xt
#pragma unroll
  for (int is = 0; is < 2; is++)
#pragma unroll
    for (int cf = 0; cf < 4; cf++) {
      int c = c0 + cf * 16 + fr;
      size_t base = ((size_t)b * CH + c) * NTOK + i0 + is * 16 + fk * 4;
      f32x4 r1 = *reinterpret_cast<const f32x4*>(xs + base);
      f32x4 r2 = *reinterpret_cast<const f32x4*>(xt + base);
      f32x4 o;
#pragma unroll
      for (int r = 0; r < 4; r++)
        o[r] = acc[is][cf][r] * rden_lds[is * 16 + fk * 4 + r] + r1[r] + r2[r];
      *reinterpret_cast<f32x4*>(out + base) = o;
    }
}

extern "C" void kernel_launch(void* const* d_in, const int* in_sizes, int n_in,
                              void* d_out, int out_size, void* d_ws, size_t ws_size,
                              hipStream_t stream) {
  const float* xs  = (const float*)d_in[0];
  const float* xt  = (const float*)d_in[1];
  const float* Wq  = (const float*)d_in[2];
  const float* bq  = (const float*)d_in[3];
  const float* Wk  = (const float*)d_in[4];
  const float* bk  = (const float*)d_in[5];
  const float* Wvs = (const float*)d_in[6];
  const float* bvs = (const float*)d_in[7];
  const float* Wvt = (const float*)d_in[8];
  const float* bvt = (const float*)d_in[9];
  float* out = (float*)d_out;

  char* ws = (char*)d_ws;
  size_t off = 0;
  unsigned short* xT = (unsigned short*)(ws + off); off += (size_t)NBATCH * NTOK * 1024 * 2;
  unsigned short* wq = (unsigned short*)(ws + off); off += (size_t)64 * 512 * 2;
  unsigned short* wk = (unsigned short*)(ws + off); off += (size_t)64 * 512 * 2;
  unsigned short* wv = (unsigned short*)(ws + off); off += (size_t)512 * 1024 * 2;
  unsigned short* Qb  = (unsigned short*)(ws + off); off += (size_t)NBATCH * NTOK * CQD * 2;
  unsigned short* Ktb = (unsigned short*)(ws + off); off += (size_t)NBATCH * NTOK * CQD * 2;
  unsigned short* Vb  = (unsigned short*)(ws + off); off += (size_t)NBATCH * CH * NTOK * 2;
  if (ws_size < off) return;  // insufficient scratch: fail safely

  k_transpose<<<dim3(NTOK / 64, 16, NBATCH), 256, 0, stream>>>(xs, xt, xT);
  k_weights<<<dim3(2304), 256, 0, stream>>>(Wq, Wk, Wvs, Wvt, wq, wk, wv);
  k_proj<<<dim3(NTOK / 256, 1, NBATCH), 256, 0, stream>>>(xT, wq, bq, nullptr, Qb, 512, 0, 0);
  k_proj<<<dim3(NTOK / 256, 1, NBATCH), 256, 0, stream>>>(xT, wk, bk, nullptr, Ktb, 512, 512, 0);
  k_proj<<<dim3(NTOK / 256, 8, NBATCH), 256, 0, stream>>>(xT, wv, bvs, bvt, Vb, 1024, 0, 1);
  k_pv<<<dim3(NTOK / IB, 2, NBATCH), 256, 0, stream>>>(Qb, Ktb, Vb, xs, xt, out);
}

// Round 7
// 286.081 us; speedup vs baseline: 1.4957x; 1.4957x over previous
//
#include <hip/hip_runtime.h>
#include <hip/hip_bf16.h>
#include <math.h>

#define NTOK 4096
#define CH 512
#define CQD 64
#define NBATCH 4
#define JB 128

typedef __bf16 bf16x8 __attribute__((ext_vector_type(8)));
typedef float f32x4 __attribute__((ext_vector_type(4)));
typedef unsigned int u32x4 __attribute__((ext_vector_type(4)));
typedef unsigned short u16x4 __attribute__((ext_vector_type(4)));

__device__ __forceinline__ unsigned short f2bf(float f) {
  unsigned int u = __builtin_bit_cast(unsigned int, f);
  unsigned int r = (u + 0x7FFFu + ((u >> 16) & 1u)) >> 16;
  return (unsigned short)r;
}

__device__ __forceinline__ bf16x8 load_frag(const unsigned short* p) {
  u32x4 v = *reinterpret_cast<const u32x4*>(p);
  return __builtin_bit_cast(bf16x8, v);
}

// ---- K0a: transpose + convert x -> xT bf16 (B, N, 1024): [0..511]=xs, [512..1023]=xt
__global__ void k_transpose(const float* __restrict__ xs, const float* __restrict__ xt,
                            unsigned short* __restrict__ xT) {
  __shared__ unsigned short lds[64][66];
  int b = blockIdx.z;
  int n0 = blockIdx.x * 64;
  int c0 = blockIdx.y * 64;  // 0..1023
  const float* src = (c0 < CH) ? xs : xt;
  int cs0 = (c0 < CH) ? c0 : c0 - CH;
  int tid = threadIdx.x;
  int nn = tid & 63, cg = tid >> 6;
  const float* base = src + ((size_t)b * CH + cs0) * NTOK + n0;
  for (int cc = cg; cc < 64; cc += 4)
    lds[cc][nn] = f2bf(base[(size_t)cc * NTOK + nn]);
  __syncthreads();
  int cw = tid & 63, ng = tid >> 6;
  unsigned short* dst = xT + ((size_t)b * NTOK + n0) * 1024 + c0 + cw;
  for (int n2 = ng; n2 < 64; n2 += 4)
    dst[(size_t)n2 * 1024] = lds[cw][n2];
}

// ---- K0b: weights f32 -> bf16 (Wq, Wk, Wv = [Wvs | Wvt])
__global__ void k_weights(const float* __restrict__ Wq, const float* __restrict__ Wk,
                          const float* __restrict__ Wvs, const float* __restrict__ Wvt,
                          unsigned short* __restrict__ wq, unsigned short* __restrict__ wk,
                          unsigned short* __restrict__ wv) {
  int t = blockIdx.x * 256 + threadIdx.x;
  if (t < 32768) {
    wq[t] = f2bf(Wq[t]);
  } else if (t < 65536) {
    int j = t - 32768;
    wk[j] = f2bf(Wk[j]);
  } else {
    int j = t - 65536;
    if (j < 512 * 1024) {
      int c = j >> 10, k = j & 1023;
      float v = (k < 512) ? Wvs[c * 512 + k] : Wvt[c * 512 + (k - 512)];
      wv[j] = f2bf(v);
    }
  }
}

// ---- K1: projection GEMM. D[n][m] = sum_k xT[b][n][koff+k] * W[m][k] (+bias)
// mode 0: out[b][n][m] (N x 64) scalar bf16 stores (for Q, Kt)
// mode 1: out[b][m][n] (C x N) packed 4-wide bf16 stores (for V)
__global__ void __launch_bounds__(256)
k_proj(const unsigned short* __restrict__ xT, const unsigned short* __restrict__ W,
       const float* __restrict__ bias1, const float* __restrict__ bias2,
       unsigned short* __restrict__ out, int Kdim, int koff, int mode) {
  int b = blockIdx.z;
  int n0 = blockIdx.x * 256;
  int m0 = blockIdx.y * 64;
  int tid = threadIdx.x;
  int w = tid >> 6, l = tid & 63;
  int fr = l & 15, fk = l >> 4;
  f32x4 acc[4][4] = {};  // [nstrip][mfrag]
  const unsigned short* xbase =
      xT + ((size_t)b * NTOK + n0 + w * 64 + fr) * 1024 + koff + fk * 8;
  const unsigned short* wbase = W + ((size_t)(m0 + fr)) * Kdim + fk * 8;
  for (int k = 0; k < Kdim; k += 32) {
    bf16x8 a[4], bb[4];
#pragma unroll
    for (int ns = 0; ns < 4; ns++) a[ns] = load_frag(xbase + (size_t)ns * 16 * 1024 + k);
#pragma unroll
    for (int mf = 0; mf < 4; mf++) bb[mf] = load_frag(wbase + (size_t)mf * 16 * Kdim + k);
#pragma unroll
    for (int ns = 0; ns < 4; ns++)
#pragma unroll
      for (int mf = 0; mf < 4; mf++)
        acc[ns][mf] = __builtin_amdgcn_mfma_f32_16x16x32_bf16(a[ns], bb[mf], acc[ns][mf], 0, 0, 0);
  }
  if (mode == 0) {
#pragma unroll
    for (int ns = 0; ns < 4; ns++)
#pragma unroll
      for (int mf = 0; mf < 4; mf++) {
        int m = m0 + mf * 16 + fr;
        float bv = bias1[m];
        int nb = n0 + w * 64 + ns * 16 + fk * 4;
#pragma unroll
        for (int r = 0; r < 4; r++)
          out[((size_t)b * NTOK + nb + r) * CQD + m] = f2bf(acc[ns][mf][r] + bv);
      }
  } else {
#pragma unroll
    for (int ns = 0; ns < 4; ns++)
#pragma unroll
      for (int mf = 0; mf < 4; mf++) {
        int c = m0 + mf * 16 + fr;
        float bv = bias1[c] + bias2[c];
        int nb = n0 + w * 64 + ns * 16 + fk * 4;
        u16x4 pk;
#pragma unroll
        for (int r = 0; r < 4; r++) pk[r] = f2bf(acc[ns][mf][r] + bv);
        *reinterpret_cast<u16x4*>(out + ((size_t)b * CH + c) * NTOK + nb) = pk;
      }
  }
}

// ---- K2: fused attention+PV, software-pipelined (R5 structure) + XCD-batch swizzle:
// flat block id -> xcd = flat&7; batch b = xcd>>1  => each XCD's working set is ONE
// batch's V (4MB) + Kt (0.5MB), L2-resident; V re-reads served from L2 not L3.
// Block: 64 i-rows x ALL 512 channels, 8 waves (wave = 64 ch + 16-j slice of P).
// Unroll-2 over j-tiles (static P0/P1), 1 barrier per tile, K/V register prefetch.
__global__ void __launch_bounds__(512, 2)
k_pv(const unsigned short* __restrict__ Q, const unsigned short* __restrict__ Kt,
     const unsigned short* __restrict__ V, const float* __restrict__ xs,
     const float* __restrict__ xt, float* __restrict__ out) {
  __shared__ __align__(16) unsigned short P0_lds[64 * JB];  // 16KB, 256B rows, XOR-swizzled
  __shared__ __align__(16) unsigned short P1_lds[64 * JB];
  __shared__ float denom_lds[8][64];
  __shared__ float rden_lds[64];
  int flat = blockIdx.x;          // 256 blocks, 1 per CU
  int xcd = flat & 7;             // heuristic: wg->XCD round-robin
  int slot = flat >> 3;
  int b = xcd >> 1;               // batch b owns XCDs {2b, 2b+1}
  int i0 = ((slot << 1) | (xcd & 1)) * 64;
  int tid = threadIdx.x;
  int w = tid >> 6;   // wave 0..7
  int l = tid & 63;
  int fr = l & 15, fk = l >> 4;
  int c0 = w * 64;

  // Q frags (B operand of S^T): col=lane&15 -> i = i0+f*16+fr, k = fk*8+e (+32 chained)
  bf16x8 qf[4][2];
#pragma unroll
  for (int f = 0; f < 4; f++) {
    const unsigned short* qb = Q + ((size_t)b * NTOK + i0 + f * 16 + fr) * CQD + fk * 8;
    qf[f][0] = load_frag(qb);
    qf[f][1] = load_frag(qb + 32);
  }
  float dsum[4] = {0.f, 0.f, 0.f, 0.f};  // per-lane partial, i = f*16 + fr
  f32x4 acc[4][4] = {};                   // [is][cf]

  // K rows (A operand of S^T): row=lane&15 -> j = jn + w*16 + fr
  const unsigned short* kbase = Kt + ((size_t)b * NTOK + w * 16 + fr) * CQD + fk * 8;
  // V rows (B operand of PV): col=lane&15 -> c = c0+cf*16+fr
  const unsigned short* vbase = V + ((size_t)b * CH + c0 + fr) * NTOK + fk * 8;

  bf16x8 kf0, kf1;     // K frags for the next phaseA tile
  bf16x8 vf[16];       // V frags for the current phaseB tile ([cf][js] flattened)

  auto loadK = [&](int jn) {
    kf0 = load_frag(kbase + (size_t)jn * CQD);
    kf1 = load_frag(kbase + (size_t)jn * CQD + 32);
  };
  auto loadV = [&](int jc) {
#pragma unroll
    for (int cf = 0; cf < 4; cf++)
#pragma unroll
      for (int js = 0; js < 4; js++)
        vf[cf * 4 + js] = load_frag(vbase + (size_t)cf * 16 * NTOK + jc + js * 32);
  };
  // phase A: P rows i0..i0+63 for j-tile at jn, into pb (uses kf0/kf1)
  auto phaseA = [&](int jn, unsigned short* plds) {
    char* pb = reinterpret_cast<char*>(plds);
#pragma unroll
    for (int f = 0; f < 4; f++) {
      f32x4 s = {};
      s = __builtin_amdgcn_mfma_f32_16x16x32_bf16(kf0, qf[f][0], s, 0, 0, 0);
      s = __builtin_amdgcn_mfma_f32_16x16x32_bf16(kf1, qf[f][1], s, 0, 0, 0);
      u16x4 pk;
#pragma unroll
      for (int r = 0; r < 4; r++) {
        float p = __expf(0.125f * s[r] - 8.0f);
        dsum[f] += p;
        pk[r] = f2bf(p);
      }
      int prow = f * 16 + fr;
      int col = w * 32 + fk * 8;  // byte col = 2*(j - jn)
      *reinterpret_cast<u16x4*>(pb + prow * (JB * 2) + (col ^ ((prow & 7) << 4))) = pk;
    }
  };
  // phase B: acc += P(64x128) @ V^T, P from plds, V from vf registers
  auto phaseB = [&](const unsigned short* plds) {
    const char* pb = reinterpret_cast<const char*>(plds);
    __builtin_amdgcn_s_setprio(1);
#pragma unroll
    for (int js = 0; js < 4; js++) {
      bf16x8 pa[4];
#pragma unroll
      for (int is = 0; is < 4; is++) {
        int prow = is * 16 + fr;
        int byteoff = prow * (JB * 2) + ((js * 64 + fk * 16) ^ ((prow & 7) << 4));
        pa[is] = __builtin_bit_cast(bf16x8, *reinterpret_cast<const u32x4*>(pb + byteoff));
      }
#pragma unroll
      for (int cf = 0; cf < 4; cf++) {
#pragma unroll
        for (int is = 0; is < 4; is++)
          acc[is][cf] =
              __builtin_amdgcn_mfma_f32_16x16x32_bf16(pa[is], vf[cf * 4 + js], acc[is][cf], 0, 0, 0);
      }
    }
    __builtin_amdgcn_s_setprio(0);
  };

  constexpr int NT = NTOK / JB;  // 32
  // ---- prologue: vf=V(0), P0=P(0), kf=K(1)
  loadK(0);
  loadV(0);
  phaseA(0, P0_lds);
  loadK(JB);
  __syncthreads();

  for (int t = 0; t < NT; t += 2) {
    // half 1: invariant P0=P(t), vf=V(t), kf=K(t+1)
    phaseA((t + 1) * JB, P1_lds);
    if (t + 2 < NT) loadK((t + 2) * JB);
    phaseB(P0_lds);
    __syncthreads();
    loadV((t + 1) * JB);
    // half 2: P1=P(t+1), vf<-V(t+1) in flight, kf=K(t+2)
    if (t + 2 < NT) {
      phaseA((t + 2) * JB, P0_lds);
      if (t + 3 < NT) loadK((t + 3) * JB);
    }
    phaseB(P1_lds);
    __syncthreads();
    if (t + 2 < NT) loadV((t + 2) * JB);
  }

  // ---- denominator: combine fk groups (lanes l, l^16, l^32, l^48 share i), then waves
#pragma unroll
  for (int f = 0; f < 4; f++) {
    float v = dsum[f];
    v += __shfl_xor(v, 16);
    v += __shfl_xor(v, 32);
    if (l < 16) denom_lds[w][f * 16 + l] = v;
  }
  __syncthreads();
  if (tid < 64) {
    float d = 0.f;
#pragma unroll
    for (int ww = 0; ww < 8; ww++) d += denom_lds[ww][tid];
    rden_lds[tid] = 1.0f / d;
  }
  __syncthreads();

  // ---- epilogue: out = acc * rden + xs + xt
#pragma unroll
  for (int is = 0; is < 4; is++)
#pragma unroll
    for (int cf = 0; cf < 4; cf++) {
      int c = c0 + cf * 16 + fr;
      size_t base = ((size_t)b * CH + c) * NTOK + i0 + is * 16 + fk * 4;
      f32x4 r1 = *reinterpret_cast<const f32x4*>(xs + base);
      f32x4 r2 = *reinterpret_cast<const f32x4*>(xt + base);
      f32x4 o;
#pragma unroll
      for (int r = 0; r < 4; r++)
        o[r] = acc[is][cf][r] * rden_lds[is * 16 + fk * 4 + r] + r1[r] + r2[r];
      *reinterpret_cast<f32x4*>(out + base) = o;
    }
}

extern "C" void kernel_launch(void* const* d_in, const int* in_sizes, int n_in,
                              void* d_out, int out_size, void* d_ws, size_t ws_size,
                              hipStream_t stream) {
  const float* xs  = (const float*)d_in[0];
  const float* xt  = (const float*)d_in[1];
  const float* Wq  = (const float*)d_in[2];
  const float* bq  = (const float*)d_in[3];
  const float* Wk  = (const float*)d_in[4];
  const float* bk  = (const float*)d_in[5];
  const float* Wvs = (const float*)d_in[6];
  const float* bvs = (const float*)d_in[7];
  const float* Wvt = (const float*)d_in[8];
  const float* bvt = (const float*)d_in[9];
  float* out = (float*)d_out;

  char* ws = (char*)d_ws;
  size_t off = 0;
  unsigned short* xT = (unsigned short*)(ws + off); off += (size_t)NBATCH * NTOK * 1024 * 2;
  unsigned short* wq = (unsigned short*)(ws + off); off += (size_t)64 * 512 * 2;
  unsigned short* wk = (unsigned short*)(ws + off); off += (size_t)64 * 512 * 2;
  unsigned short* wv = (unsigned short*)(ws + off); off += (size_t)512 * 1024 * 2;
  unsigned short* Qb  = (unsigned short*)(ws + off); off += (size_t)NBATCH * NTOK * CQD * 2;
  unsigned short* Ktb = (unsigned short*)(ws + off); off += (size_t)NBATCH * NTOK * CQD * 2;
  unsigned short* Vb  = (unsigned short*)(ws + off); off += (size_t)NBATCH * CH * NTOK * 2;
  if (ws_size < off) return;  // insufficient scratch: fail safely

  k_transpose<<<dim3(NTOK / 64, 16, NBATCH), 256, 0, stream>>>(xs, xt, xT);
  k_weights<<<dim3(2304), 256, 0, stream>>>(Wq, Wk, Wvs, Wvt, wq, wk, wv);
  k_proj<<<dim3(NTOK / 256, 1, NBATCH), 256, 0, stream>>>(xT, wq, bq, nullptr, Qb, 512, 0, 0);
  k_proj<<<dim3(NTOK / 256, 1, NBATCH), 256, 0, stream>>>(xT, wk, bk, nullptr, Ktb, 512, 512, 0);
  k_proj<<<dim3(NTOK / 256, 8, NBATCH), 256, 0, stream>>>(xT, wv, bvs, bvt, Vb, 1024, 0, 1);
  k_pv<<<dim3(NTOK / 64 * NBATCH), 512, 0, stream>>>(Qb, Ktb, Vb, xs, xt, out);
}